// Round 1
// baseline (1822.625 us; speedup 1.0000x reference)
//
#include <hip/hip_runtime.h>
#include <hip/hip_bf16.h>
#include <math.h>

#define NXF 2048          // x is 2048 x 2048
#define TAB_ROWS 4104     // 4095 real diag rows (+ padding for prefetch), zero-filled beyond
#define NITER 4096        // DP diagonals 0..4092, contributions through 4094, 4095 no-op

// ---------------------------------------------------------------------------
// Prologue: skew exp(x) into diag-major table: tab[i][p] = exp(x[a][b]) where
// a = ((2046+i)>>1) - p, b = i - a, zero outside the 2048x2048 grid.
// ---------------------------------------------------------------------------
__global__ void es_precompute_kernel(const float* __restrict__ x, float* __restrict__ tab) {
  const int p = blockIdx.x * blockDim.x + threadIdx.x;   // [0,2048)
  const int i = blockIdx.y;                              // [0,TAB_ROWS)
  const int a = ((2046 + i) >> 1) - p;
  const int b = i - a;
  float v = 0.f;
  if ((unsigned)a < 2048u && (unsigned)b < 2048u)
    v = __expf(x[a * NXF + b]);
  tab[(size_t)i * NXF + p] = v;
}

// ---------------------------------------------------------------------------
// Persistent single-workgroup wavefront sweep in exp space.
// 1024 threads, thread t owns slots p0=2t, p1=2t+1 (slot 2047 is a dummy,
// forced to 0 = NEG_INF). Carries per slot: (M1,X1,Y1,S1) of diag i-1 and
// S2 of diag i-2, all in registers. Neighbor (+-1 slot) values via shuffles;
// wave-boundary values via small double-buffered LDS. One barrier per diag.
// Block-wide power-of-2 rescale every 8 diagonals, tracked in Lof.
// ---------------------------------------------------------------------------
template<bool USE_TAB>
__global__ __launch_bounds__(1024) void sw_dp_kernel(const float* __restrict__ x,
                                                     const float* __restrict__ tab,
                                                     float* __restrict__ out) {
  const int tid  = threadIdx.x;
  const int lane = tid & 63;
  const int wv   = tid >> 6;     // 16 waves
  const int p0   = tid * 2;
  const int p1   = p0 + 1;

  __shared__ float eUp[2][16][2];   // [buf][wave] : (M,X) of wave's last slot (lane63.slot1)
  __shared__ float eDn[2][16][3];   // [buf][wave] : (M,X,Y) of wave's first slot (lane0.slot0)
  __shared__ float red[16];         // rescale max reduction
  __shared__ float wsum[16];        // final sum reduction

  if (tid < 16) {
    eUp[0][tid][0] = 0.f; eUp[0][tid][1] = 0.f;
    eDn[0][tid][0] = 0.f; eDn[0][tid][1] = 0.f; eDn[0][tid][2] = 0.f;
  }
  __syncthreads();

  float M1a=0.f, X1a=0.f, Y1a=0.f, S1a=0.f, S2a=0.f;
  float M1b=0.f, X1b=0.f, Y1b=0.f, S1b=0.f, S2b=0.f;
  float acc = 0.f;        // running sum of S[i-2][p]*exp(x[a+1][b+1]) (stored units)
  float one = 1.f;        // exp(-Lof): the "start fresh" +1 term in stored units
  float Lof = 0.f;        // log scale offset: true = stored * exp(Lof)
  float tmx = 0.f;        // running max of S0 since last rescale
  float escale = 1.f;     // applies to LDS edge values written pre-rescale

  const float cGO = 0.006737946999085467f;   // exp(GAP_OPEN = -5)
  const float cGE = 0.36787944117144233f;    // exp(GAP_EXTEND = -1)

  auto ldrow = [&](int i) -> float2 {
    if (USE_TAB) {
      return *reinterpret_cast<const float2*>(tab + (size_t)i * NXF + p0);
    } else {
      int a0 = ((2046 + i) >> 1) - p0;
      int b0 = i - a0;
      float2 r;
      r.x = ((unsigned)a0 < 2048u && (unsigned)b0 < 2048u) ? x[a0 * NXF + b0] : -1e30f;
      int a1 = a0 - 1, b1 = b0 + 1;
      r.y = ((unsigned)a1 < 2048u && (unsigned)b1 < 2048u) ? x[a1 * NXF + b1] : -1e30f;
      return r;
    }
  };
  auto cvt = [&](float raw) -> float {
    if (USE_TAB) return raw;
    return (raw > -1e29f) ? __expf(raw) : 0.f;
  };

  auto body = [&](int i, float2 esr, bool even) {
    const int buf  = i & 1;
    const int nbuf = buf ^ 1;
    const int base = (2046 + i) >> 1;
    const int aHi  = (i < 2046) ? i : 2046;
    const int aLo  = (i > 2046) ? (i - 2046) : 0;
    const int pLoV = base - aHi;       // DP-active slot range [pLoV, pHiV]
    const int pHiV = base - aLo;

    const float esf0 = cvt(esr.x);     // full-grid exp(x) (for the final-sum FMA)
    const float esf1 = cvt(esr.y);

    // fused final reduction: cell (a-1,b-1) of diag i-2 contributes S2 * exp(x[a][b])
    acc = fmaf(esf0, S2a, acc);
    acc = fmaf(esf1, S2b, acc);

    const float esd0 = (p0 >= pLoV && p0 <= pHiV) ? esf0 : 0.f;  // DP-masked
    const float esd1 = (p1 >= pLoV && p1 <= pHiV) ? esf1 : 0.f;

    // align (diag i-2, same slot) + fresh-start term
    float M0a = esd0 * (S2a + one);
    float M0b = esd1 * (S2b + one);

    // gather west (needs M,X) and north (needs M,X,Y) predecessors from diag i-1
    float wM0, wX0, nM0, nX0, nY0, wM1, wX1, nM1, nX1, nY1;
    if (even) {   // so = 1 : west = h1[p-1], north = h1[p]
      float uM = __shfl_up(M1b, 1);
      float uX = __shfl_up(X1b, 1);
      if (lane == 0) {
        if (wv > 0) { uM = eUp[buf][wv-1][0] * escale; uX = eUp[buf][wv-1][1] * escale; }
        else        { uM = 0.f; uX = 0.f; }
      }
      wM0 = uM;   wX0 = uX;   nM0 = M1a;  nX0 = X1a;  nY0 = Y1a;
      wM1 = M1a;  wX1 = X1a;  nM1 = M1b;  nX1 = X1b;  nY1 = Y1b;
    } else {      // so = 0 : west = h1[p], north = h1[p+1]
      float dM = __shfl_down(M1a, 1);
      float dX = __shfl_down(X1a, 1);
      float dY = __shfl_down(Y1a, 1);
      if (lane == 63) {
        if (wv < 15) { dM = eDn[buf][wv+1][0] * escale; dX = eDn[buf][wv+1][1] * escale; dY = eDn[buf][wv+1][2] * escale; }
        else         { dM = 0.f; dX = 0.f; dY = 0.f; }
      }
      wM0 = M1a;  wX0 = X1a;  nM0 = M1b;  nX0 = X1b;  nY0 = Y1b;
      wM1 = M1b;  wX1 = X1b;  nM1 = dM;   nX1 = dX;   nY1 = dY;
    }

    float X0a = fmaf(cGO, wM0, cGE * wX0);
    float X0b = fmaf(cGO, wM1, cGE * wX1);
    float Y0a = fmaf(cGO, nM0 + nX0, cGE * nY0);
    float Y0b = fmaf(cGO, nM1 + nX1, cGE * nY1);

    float S0a = M0a + X0a + Y0a;
    float S0b = M0b + X0b + Y0b;

    if (p1 == 2047) { M0b = 0.f; X0b = 0.f; Y0b = 0.f; S0b = 0.f; }  // dummy slot = NEG_INF

    tmx = fmaxf(tmx, fmaxf(S0a, S0b));

    // rotate carries
    S2a = S1a; S2b = S1b;
    M1a = M0a; X1a = X0a; Y1a = Y0a; S1a = S0a;
    M1b = M0b; X1b = X0b; Y1b = Y0b; S1b = S0b;

    // publish wave-edge values of the new h1 for the next diagonal
    if (lane == 63) { eUp[nbuf][wv][0] = M1b; eUp[nbuf][wv][1] = X1b; }
    if (lane == 0)  { eDn[nbuf][wv][0] = M1a; eDn[nbuf][wv][1] = X1a; eDn[nbuf][wv][2] = Y1a; }

    const bool doResc = ((i & 7) == 7);
    if (doResc) {
      float m = tmx;
      #pragma unroll
      for (int off = 32; off; off >>= 1) m = fmaxf(m, __shfl_xor(m, off));
      if (lane == 0) red[wv] = m;
    }
    __syncthreads();
    escale = 1.f;
    if (doResc) {
      float m = red[0];
      #pragma unroll
      for (int k = 1; k < 16; k++) m = fmaxf(m, red[k]);
      tmx = 0.f;
      if (m > 0.f) {
        int e = ilogbf(m);
        if (e != 0) {
          float c = exp2f((float)(-e));
          M1a *= c; X1a *= c; Y1a *= c; S1a *= c; S2a *= c;
          M1b *= c; X1b *= c; Y1b *= c; S1b *= c; S2b *= c;
          acc *= c; one *= c; escale = c;
          Lof += (float)e * 0.6931471805599453f;
        }
      }
    }
  };

  // software-pipelined main loop: 4 diagonals in flight
  float2 e0 = ldrow(0), e1 = ldrow(1), e2 = ldrow(2), e3 = ldrow(3);
  for (int it = 0; it < NITER; it += 4) {
    body(it + 0, e0, true );  e0 = ldrow(it + 4);
    body(it + 1, e1, false);  e1 = ldrow(it + 5);
    body(it + 2, e2, true );  e2 = ldrow(it + 6);
    body(it + 3, e3, false);  e3 = ldrow(it + 7);
  }

  // final reduction: result = log(sum acc) + Lof
  float s = acc;
  #pragma unroll
  for (int off = 32; off; off >>= 1) s += __shfl_xor(s, off);
  if (lane == 0) wsum[wv] = s;
  __syncthreads();
  if (tid == 0) {
    float t = 0.f;
    #pragma unroll
    for (int k = 0; k < 16; k++) t += wsum[k];
    out[0] = logf(t) + Lof;
  }
}

extern "C" void kernel_launch(void* const* d_in, const int* in_sizes, int n_in,
                              void* d_out, int out_size, void* d_ws, size_t ws_size,
                              hipStream_t stream) {
  const float* x = (const float*)d_in[0];
  float* out = (float*)d_out;
  float* tab = (float*)d_ws;
  const size_t need = (size_t)TAB_ROWS * NXF * sizeof(float);
  if (ws_size >= need) {
    dim3 g(NXF / 256, TAB_ROWS);
    es_precompute_kernel<<<g, dim3(256), 0, stream>>>(x, tab);
    sw_dp_kernel<true><<<1, dim3(1024), 0, stream>>>(x, tab, out);
  } else {
    sw_dp_kernel<false><<<1, dim3(1024), 0, stream>>>(x, nullptr, out);
  }
}

// Round 2
// 1690.411 us; speedup vs baseline: 1.0782x; 1.0782x over previous
//
#include <hip/hip_runtime.h>
#include <hip/hip_bf16.h>
#include <math.h>

#define NXF 2048          // x is 2048 x 2048
#define TAB_ROWS 4104     // 4095 real diag rows + prefetch pad (zero-filled)
#define NITER 4096        // bodies 0..4095; last real contribution at i=4094
#define NT 512            // threads (8 waves)
#define NW 8

// ---------------------------------------------------------------------------
// Prologue: skew exp(x) into diag-major table with DP-activity in the SIGN:
//   tab[i][p] = exp(x[a][b])  (a,b in [0,2047], else 0),  negated when the
//   cell is NOT DP-active (DP grid = xin = x[:-1,:-1], i.e. a,b in [0,2046]).
// a = ((2046+i)>>1) - p, b = i - a.
// ---------------------------------------------------------------------------
__global__ void es_precompute_kernel(const float* __restrict__ x, float* __restrict__ tab) {
  const int p = blockIdx.x * blockDim.x + threadIdx.x;   // [0,2048)
  const int i = blockIdx.y;                              // [0,TAB_ROWS)
  const int a = ((2046 + i) >> 1) - p;
  const int b = i - a;
  float v = 0.f;
  if ((unsigned)a < 2048u && (unsigned)b < 2048u) {
    v = __expf(x[a * NXF + b]);
    if (!((unsigned)a < 2047u && (unsigned)b < 2047u)) v = -v;  // full-grid but not DP
  }
  tab[(size_t)i * NXF + p] = v;
}

// ---------------------------------------------------------------------------
// Persistent single-workgroup wavefront sweep in exp space.
// 512 threads x 4 slots (slot p = 4*tid+s). Carries per slot: T=M+X, X, Y,
// S=T+Y of diag i-1, plus S of diag i-2. Exp-space linear recurrence:
//   M0 = esd*(S2 + one);  X0 = cGO*wT + (cGE-cGO)*wX;  Y0 = cGO*nT + cGE*nY
// Intra-thread neighbors are register-local; one shuffle pair per diagonal;
// wave boundaries via tiny double-buffered LDS. Waves outside the active
// window (union of DP windows at i and i-2) skip to the barrier.
// Block-wide power-of-2 rescale every 16 diagonals tracked in Lof; final
// logsumexp is fused as acc += esf * S2 each diagonal.
// ---------------------------------------------------------------------------
template<bool USE_TAB>
__global__ __launch_bounds__(NT) void sw_dp_kernel(const float* __restrict__ x,
                                                   const float* __restrict__ tab,
                                                   float* __restrict__ out) {
  const int tid  = threadIdx.x;
  const int lane = tid & 63;
  const int wv   = __builtin_amdgcn_readfirstlane(tid >> 6);
  const int p0   = tid * 4;

  __shared__ float eUp[2][NW][2];   // [buf][wave] : (T,X) of wave's last slot
  __shared__ float eDn[2][NW][2];   // [buf][wave] : (T,Y) of wave's first slot
  __shared__ float red[NW];         // rescale max reduction
  __shared__ float wsum[NW];        // final sum reduction

  if (tid < 2 * NW) {
    int bu = tid >> 3, w = tid & 7;
    eUp[bu][w][0] = 0.f; eUp[bu][w][1] = 0.f;
    eDn[bu][w][0] = 0.f; eDn[bu][w][1] = 0.f;
  }
  __syncthreads();

  float T1a=0.f,T1b=0.f,T1c=0.f,T1d=0.f;
  float X1a=0.f,X1b=0.f,X1c=0.f,X1d=0.f;
  float Y1a=0.f,Y1b=0.f,Y1c=0.f,Y1d=0.f;
  float S1a=0.f,S1b=0.f,S1c=0.f,S1d=0.f;
  float S2a=0.f,S2b=0.f,S2c=0.f,S2d=0.f;
  float acc = 0.f;        // running sum of S2 * exp(x) (stored units)
  float one = 1.f;        // exp(-Lof): fresh-start term in stored units
  float Lof = 0.f;        // log scale offset
  float tmx = 0.f;        // running max since last rescale
  float escale = 1.f;     // scale fix for LDS edges published pre-rescale

  const float kmask = (tid == NT - 1) ? 0.f : 1.f;   // slot 2047 is a dummy
  const float cGO = 0.006737946999085467f;           // exp(-5)
  const float cGE = 0.36787944117144233f;            // exp(-1)
  const float kX  = cGE - cGO;

  auto ldraw = [&](int i) -> float4 {
    if constexpr (USE_TAB) {
      return *reinterpret_cast<const float4*>(tab + (size_t)i * NXF + p0);
    } else {
      float4 r; float* rp = &r.x;
      #pragma unroll
      for (int s = 0; s < 4; ++s) {
        int p = p0 + s;
        int a = ((2046 + i) >> 1) - p;
        int b = i - a;
        float v = 0.f;
        if ((unsigned)a < 2048u && (unsigned)b < 2048u) {
          v = __expf(x[a * NXF + b]);
          if (!((unsigned)a < 2047u && (unsigned)b < 2047u)) v = -v;
        }
        rp[s] = v;
      }
      return r;
    }
  };

  auto body = [&](int i, float4 e, bool even) {
    const int buf  = i & 1;
    const int nbuf = buf ^ 1;
    const bool doResc = ((i & 15) == 15);

    // wave-uniform activity: union of DP windows at diag i and i-2
    const int base = (2046 + i) >> 1;
    const int aHi  = (i < 2046) ? i : 2046;
    const int aLo  = (i > 2046) ? (i - 2046) : 0;
    int pLo = base - aHi, pHi = base - aLo;
    if (i >= 2) {
      const int i2    = i - 2;
      const int base2 = (2046 + i2) >> 1;
      const int aHi2  = (i2 < 2046) ? i2 : 2046;
      const int aLo2  = (i2 > 2046) ? (i2 - 2046) : 0;
      const int pLo2 = base2 - aHi2, pHi2 = base2 - aLo2;
      pLo = (pLo2 < pLo) ? pLo2 : pLo;
      pHi = (pHi2 > pHi) ? pHi2 : pHi;
    }
    const int  w0  = wv << 8;
    const bool act = (w0 + 255 >= pLo) && (w0 <= pHi);

    if (act) {
      // cvt: |v| = full-grid exp(x); max(v,0) = DP-masked exp(x)
      const float esfa = fabsf(e.x), esfb = fabsf(e.y), esfc = fabsf(e.z), esfd = fabsf(e.w);
      const float esda = fmaxf(e.x, 0.f), esdb = fmaxf(e.y, 0.f);
      const float esdc = fmaxf(e.z, 0.f), esdd = fmaxf(e.w, 0.f);
      const float e1a = esda * one, e1b = esdb * one, e1c = esdc * one, e1d = esdd * one;

      // fused final reduction
      acc = fmaf(esfa, S2a, acc); acc = fmaf(esfb, S2b, acc);
      acc = fmaf(esfc, S2c, acc); acc = fmaf(esfd, S2d, acc);

      const float M0a = fmaf(esda, S2a, e1a), M0b = fmaf(esdb, S2b, e1b);
      const float M0c = fmaf(esdc, S2c, e1c), M0d = fmaf(esdd, S2d, e1d);

      float X0a, X0b, X0c, X0d, Y0a, Y0b, Y0c, Y0d;
      if (even) {   // so = 1 : west = h1[p-1], north = h1[p] (self)
        float uT = __shfl_up(T1d, 1), uX = __shfl_up(X1d, 1);
        const int wn = (wv > 0) ? wv - 1 : 0;
        if (lane == 0) {
          uT = wv ? eUp[buf][wn][0] * escale : 0.f;
          uX = wv ? eUp[buf][wn][1] * escale : 0.f;
        }
        X0a = fmaf(cGO, uT,  kX * uX);
        X0b = fmaf(cGO, T1a, kX * X1a);
        X0c = fmaf(cGO, T1b, kX * X1b);
        X0d = fmaf(cGO, T1c, kX * X1c);
        Y0a = fmaf(cGO, T1a, cGE * Y1a);
        Y0b = fmaf(cGO, T1b, cGE * Y1b);
        Y0c = fmaf(cGO, T1c, cGE * Y1c);
        Y0d = fmaf(cGO, T1d, cGE * Y1d);
      } else {      // so = 0 : west = h1[p] (self), north = h1[p+1]
        float dT = __shfl_down(T1a, 1), dY = __shfl_down(Y1a, 1);
        const int wn = (wv < NW - 1) ? wv + 1 : NW - 1;
        if (lane == 63) {
          dT = (wv < NW - 1) ? eDn[buf][wn][0] * escale : 0.f;
          dY = (wv < NW - 1) ? eDn[buf][wn][1] * escale : 0.f;
        }
        X0a = fmaf(cGO, T1a, kX * X1a);
        X0b = fmaf(cGO, T1b, kX * X1b);
        X0c = fmaf(cGO, T1c, kX * X1c);
        X0d = fmaf(cGO, T1d, kX * X1d);
        Y0a = fmaf(cGO, T1b, cGE * Y1b);
        Y0b = fmaf(cGO, T1c, cGE * Y1c);
        Y0c = fmaf(cGO, T1d, cGE * Y1d);
        Y0d = fmaf(cGO, dT,  cGE * dY);
      }

      const float T0a = M0a + X0a, T0b = M0b + X0b, T0c = M0c + X0c;
      const float T0d = (M0d + X0d) * kmask;          // keep dummy slot at 0
      const float S0a = T0a + Y0a, S0b = T0b + Y0b;
      const float S0c = T0c + Y0c, S0d = T0d + Y0d;

      tmx = fmaxf(tmx, fmaxf(fmaxf(S0a, S0b), fmaxf(S0c, S0d)));

      // rotate carries
      S2a = S1a; S2b = S1b; S2c = S1c; S2d = S1d;
      S1a = S0a; S1b = S0b; S1c = S0c; S1d = S0d;
      T1a = T0a; T1b = T0b; T1c = T0c; T1d = T0d;
      X1a = X0a; X1b = X0b; X1c = X0c; X1d = X0d;
      Y1a = Y0a; Y1b = Y0b; Y1c = Y0c; Y1d = Y0d;

      // publish the edge the NEXT diagonal needs
      if (even) {
        if (lane == 0)  { eDn[nbuf][wv][0] = T1a; eDn[nbuf][wv][1] = Y1a; }
      } else {
        if (lane == 63) { eUp[nbuf][wv][0] = T1d; eUp[nbuf][wv][1] = X1d; }
      }

      if (doResc) {
        float m = tmx;
        #pragma unroll
        for (int off = 32; off; off >>= 1) m = fmaxf(m, __shfl_xor(m, off));
        if (lane == 0) red[wv] = m;
      }
    } else if (doResc && lane == 0) {
      red[wv] = 0.f;
    }

    __syncthreads();

    escale = 1.f;
    if (doResc) {
      float m = red[lane & (NW - 1)];
      m = fmaxf(m, __shfl_xor(m, 1));
      m = fmaxf(m, __shfl_xor(m, 2));
      m = fmaxf(m, __shfl_xor(m, 4));
      tmx = 0.f;
      if (m > 0.f) {
        int ex = ilogbf(m);
        if (ex < -126) ex = -126;
        if (ex != 0) {
          const float c = exp2f((float)(-ex));
          T1a*=c;T1b*=c;T1c*=c;T1d*=c;
          X1a*=c;X1b*=c;X1c*=c;X1d*=c;
          Y1a*=c;Y1b*=c;Y1c*=c;Y1d*=c;
          S1a*=c;S1b*=c;S1c*=c;S1d*=c;
          S2a*=c;S2b*=c;S2c*=c;S2d*=c;
          acc*=c; one*=c; escale=c;
          Lof += (float)ex * 0.6931471805599453f;
        }
      }
    }
  };

  // software-pipelined main loop: 4 diagonals in flight
  float4 e0 = ldraw(0), e1 = ldraw(1), e2 = ldraw(2), e3 = ldraw(3);
  for (int it = 0; it < NITER; it += 4) {
    body(it + 0, e0, true );  e0 = ldraw(it + 4);
    body(it + 1, e1, false);  e1 = ldraw(it + 5);
    body(it + 2, e2, true );  e2 = ldraw(it + 6);
    body(it + 3, e3, false);  e3 = ldraw(it + 7);
  }

  // final reduction: result = log(sum acc) + Lof
  float s = acc;
  #pragma unroll
  for (int off = 32; off; off >>= 1) s += __shfl_xor(s, off);
  if (lane == 0) wsum[wv] = s;
  __syncthreads();
  if (tid == 0) {
    float t = 0.f;
    #pragma unroll
    for (int k = 0; k < NW; k++) t += wsum[k];
    out[0] = logf(t) + Lof;
  }
}

extern "C" void kernel_launch(void* const* d_in, const int* in_sizes, int n_in,
                              void* d_out, int out_size, void* d_ws, size_t ws_size,
                              hipStream_t stream) {
  const float* x = (const float*)d_in[0];
  float* out = (float*)d_out;
  float* tab = (float*)d_ws;
  const size_t need = (size_t)TAB_ROWS * NXF * sizeof(float);
  if (ws_size >= need) {
    dim3 g(NXF / 256, TAB_ROWS);
    es_precompute_kernel<<<g, dim3(256), 0, stream>>>(x, tab);
    sw_dp_kernel<true><<<1, dim3(NT), 0, stream>>>(x, tab, out);
  } else {
    sw_dp_kernel<false><<<1, dim3(NT), 0, stream>>>(x, nullptr, out);
  }
}

// Round 5
// 781.988 us; speedup vs baseline: 2.3308x; 2.1617x over previous
//
#include <hip/hip_runtime.h>
#include <hip/hip_bf16.h>
#include <math.h>

#define N 2048            // x is 2048 x 2048 (DP grid = [0,2046]^2; row/col 2047 feed acc only)
#define NW 4              // 4 waves, one per SIMD, single workgroup
#define CPL 8             // columns per lane (4*64*8 = 2048)
#define RPS 4             // rows per wave per step
#define SPW (N / RPS)     // 512 active steps per wave
#define NSTEP (SPW + NW - 1)   // 515 total (systolic skew depth NW-1)

// ---------------------------------------------------------------------------
// Prologue: tab = exp(x), row-major, fully parallel & coalesced.
// ---------------------------------------------------------------------------
__global__ void exp_table_kernel(const float* __restrict__ x, float* __restrict__ tab) {
  int i = blockIdx.x * blockDim.x + threadIdx.x;
  const int n4 = N * N / 4;
  const float4* xv = (const float4*)x;
  float4* tv = (float4*)tab;
  for (; i < n4; i += gridDim.x * blockDim.x) {
    float4 v = xv[i];
    float4 r;
    r.x = __expf(v.x); r.y = __expf(v.y); r.z = __expf(v.z); r.w = __expf(v.w);
    tv[i] = r;
  }
}

// ---------------------------------------------------------------------------
// Systolic row-sweep soft SW in exp space. Wave w owns columns [512w,512w+512),
// processes rows RPS*(s-w)..+3 at step s (one step behind wave w-1), so the
// same-row left edge {S, X, Mg} it consumes was published by wave w-1 LAST
// step -> available after the single per-step __syncthreads(). Parity double-
// buffered edges; ONE shared block exponent (max over all waves, identical
// rescale factor in every wave every 4 steps = 16 rows); escale fixes edges
// published pre-rescale. Only R1/R2-verified sync mechanisms; no atomics.
// Recurrence per cell (verified vs reference in R2, exp space, T = M+X):
//   M = es*(S_diag + one); X = cGE*X_w + cGO*M_w; Y = cGO*T_n + cGE*Y_n;
//   S = M+X+Y;  acc += es*S_diag  (fused final logsumexp numerator).
// X cross-lane seed: 2-term truncation (error e^-16).
// ---------------------------------------------------------------------------
template<bool USE_TAB>
__global__ __launch_bounds__(256) void sw_sys_kernel(const float* __restrict__ x,
                                                     const float* __restrict__ tab,
                                                     float* __restrict__ out) {
  const int tid  = threadIdx.x;
  const int lane = tid & 63;
  const int w    = tid >> 6;                 // 0..3, wave-uniform
  const int c0   = (w << 9) + lane * CPL;    // lane's first column

  __shared__ float4 edges[2][NW][RPS];       // [step parity][wave][row-in-step] = {S, X, Mg, 0}
  __shared__ float  red[NW];                 // rescale max
  __shared__ float  wsum[NW];                // final sum

  const float cGO = 0.006737946999085467f;   // e^-5
  const float cGE = 0.36787944117144233f;    // e^-1
  const float C8  = 0.00033546262790251185f; // e^-8
  constexpr float KC[CPL] = {                // cGE^(j+1)
    0.36787944117144233f, 0.1353352832366127f, 0.049787068367863944f,
    0.01831563888873418f, 0.006737946999085467f, 0.0024787521766663585f,
    0.0009118819655545162f, 0.00033546262790251185f };

  float S1[CPL], Tc[CPL], Yc[CPL];
  #pragma unroll
  for (int j = 0; j < CPL; ++j) { S1[j] = 0.f; Tc[j] = 0.f; Yc[j] = 0.f; }

  float acc = 0.f;      // running sum of S_diag*es (stored units)
  float one = 1.f;      // exp2(-Etot): fresh-start term in stored units
  float Lof = 0.f;      // log scale offset (identical in all waves)
  float tmx = 0.f;      // running max since last rescale
  float escale = 1.f;   // unit fix for edges published pre-rescale
  float SinC = 0.f;     // S_edge(r0-1) carry for next step's first row

  const float* src = USE_TAB ? tab : x;
  auto ldrow = [&](int r, float4& f0, float4& f1) {
    int rr = r; if (rr < 0) rr = 0; if (rr > N - 1) rr = N - 1;
    const float* p = src + (size_t)rr * N + c0;
    f0 = *(const float4*)(p);
    f1 = *(const float4*)(p + 4);
  };

  // preload first active step's rows (rows 0..3 for every wave)
  float4 nx[RPS][2];
  #pragma unroll
  for (int k = 0; k < RPS; ++k) ldrow(k, nx[k][0], nx[k][1]);

  for (int s = 0; s < NSTEP; ++s) {
    const bool act    = (s >= w) && (s < w + SPW);
    const bool doResc = ((s & 3) == 3);      // every 4 steps = 16 rows

    if (act) {
      // rotate prefetch, issue next step's loads (clamped; unused rows harmless)
      float4 cur[RPS][2];
      #pragma unroll
      for (int k = 0; k < RPS; ++k) { cur[k][0] = nx[k][0]; cur[k][1] = nx[k][1]; }
      const int r0n = RPS * (s + 1 - w);
      #pragma unroll
      for (int k = 0; k < RPS; ++k) ldrow(r0n + k, nx[k][0], nx[k][1]);

      // consume left edges (published by wave w-1 last step, other parity buffer)
      float Sr[RPS], Xi[RPS], Mgi[RPS];
      float SinNext = 0.f;
      if (w > 0) {
        const int cr = (s & 1) ^ 1;
        float4 e0 = edges[cr][w-1][0];
        float4 e1 = edges[cr][w-1][1];
        float4 e2 = edges[cr][w-1][2];
        float4 e3 = edges[cr][w-1][3];
        Sr[0] = SinC;             // S_edge(r0-1), carried from last step
        Sr[1] = e0.x * escale;
        Sr[2] = e1.x * escale;
        Sr[3] = e2.x * escale;
        SinNext = e3.x * escale;
        Xi[0] = e0.y * escale;  Mgi[0] = e0.z * escale;
        Xi[1] = e1.y * escale;  Mgi[1] = e1.z * escale;
        Xi[2] = e2.y * escale;  Mgi[2] = e2.z * escale;
        Xi[3] = e3.y * escale;  Mgi[3] = e3.z * escale;
      } else {
        #pragma unroll
        for (int k = 0; k < RPS; ++k) { Sr[k] = 0.f; Xi[k] = 0.f; Mgi[k] = 0.f; }
      }

      const int pr = s & 1;
      #pragma unroll
      for (int k = 0; k < RPS; ++k) {
        float es[CPL] = { cur[k][0].x, cur[k][0].y, cur[k][0].z, cur[k][0].w,
                          cur[k][1].x, cur[k][1].y, cur[k][1].z, cur[k][1].w };
        if constexpr (!USE_TAB) {
          #pragma unroll
          for (int j = 0; j < CPL; ++j) es[j] = __expf(es[j]);
        }
        // M / acc (needs prev-row S shifted right by one column)
        float sh  = __shfl_up(S1[CPL-1], 1);
        float s1s = (lane == 0) ? Sr[k] : sh;
        float M[CPL], Mg[CPL];
        #pragma unroll
        for (int j = 0; j < CPL; ++j) {
          acc   = fmaf(es[j], s1s, acc);
          M[j]  = es[j] * (s1s + one);
          Mg[j] = cGO * M[j];
          s1s   = S1[j];
        }
        // X: local chain + 2-term truncated lane seed (exact for lanes 0,1)
        float mgp = __shfl_up(Mg[CPL-1], 1);
        if (lane == 0) mgp = Mgi[k];
        float Xl[CPL];
        Xl[0] = mgp;
        #pragma unroll
        for (int j = 1; j < CPL; ++j) Xl[j] = fmaf(cGE, Xl[j-1], Mg[j-1]);
        float xt = Xl[CPL-1];
        float u1 = __shfl_up(xt, 1);
        float u2 = __shfl_up(xt, 2);
        if (lane == 0) { u1 = Xi[k]; u2 = 0.f; }
        if (lane == 1) { u2 = Xi[k]; }
        float seed = fmaf(C8, u2, u1);
        // T / Y / S
        #pragma unroll
        for (int j = 0; j < CPL; ++j) {
          float T  = fmaf(KC[j], seed, M[j] + Xl[j]);
          float Yv = fmaf(cGE, Yc[j], cGO * Tc[j]);
          float S  = T + Yv;
          tmx = fmaxf(tmx, S);
          Tc[j] = T; Yc[j] = Yv; S1[j] = S;
        }
        // publish this row's right edge for wave w+1 (consumed next step)
        if (w < NW - 1 && lane == 63) {
          float xp = fmaf(KC[CPL-1], seed, Xl[CPL-1]);   // true X at last col
          edges[pr][w][k] = make_float4(S1[CPL-1], xp, Mg[CPL-1], 0.f);
        }
      }
      if (w > 0) SinC = SinNext;
    }

    if (doResc) {
      float m = tmx;
      #pragma unroll
      for (int off = 1; off < 64; off <<= 1) m = fmaxf(m, __shfl_xor(m, off));
      if (lane == 0) red[w] = m;   // inactive waves publish 0 (tmx stays 0)
    }

    __syncthreads();               // edges + red visible; WAR-safe via parity

    escale = 1.f;
    if (doResc) {
      float m = fmaxf(fmaxf(red[0], red[1]), fmaxf(red[2], red[3]));
      tmx = 0.f;
      int e = (m > 0.f) ? ilogbf(m) : 0;
      if (e > 120) e = 120;
      if (e < -120) e = -120;
      if (e != 0) {                // identical in every wave -> shared exponent
        float c = exp2f((float)(-e));
        #pragma unroll
        for (int j = 0; j < CPL; ++j) { S1[j] *= c; Tc[j] *= c; Yc[j] *= c; }
        acc *= c; one *= c; SinC *= c;
        escale = c;
        Lof += (float)e * 0.6931471805599453f;
      }
    }
  }

  // final reduction: all waves share Lof; result = log(sum acc) + Lof
  float ssum = acc;
  #pragma unroll
  for (int off = 1; off < 64; off <<= 1) ssum += __shfl_xor(ssum, off);
  if (lane == 0) wsum[w] = ssum;
  __syncthreads();
  if (tid == 0) {
    double tot = (double)wsum[0] + (double)wsum[1] + (double)wsum[2] + (double)wsum[3];
    out[0] = (float)(log(tot) + (double)Lof);
  }
}

extern "C" void kernel_launch(void* const* d_in, const int* in_sizes, int n_in,
                              void* d_out, int out_size, void* d_ws, size_t ws_size,
                              hipStream_t stream) {
  const float* x = (const float*)d_in[0];
  float* out = (float*)d_out;
  float* tab = (float*)d_ws;
  const size_t need = (size_t)N * N * sizeof(float);
  if (ws_size >= need) {
    exp_table_kernel<<<1024, dim3(256), 0, stream>>>(x, tab);
    sw_sys_kernel<true><<<1, dim3(256), 0, stream>>>(x, tab, out);
  } else {
    sw_sys_kernel<false><<<1, dim3(256), 0, stream>>>(x, nullptr, out);
  }
}

// Round 6
// 554.170 us; speedup vs baseline: 3.2889x; 1.4111x over previous
//
#include <hip/hip_runtime.h>
#include <hip/hip_bf16.h>
#include <math.h>

#define N 2048            // x is 2048 x 2048 (DP grid = [0,2046]^2)
#define PADR 8            // zero pad rows in tab so prefetch never clamps
#define NW 8              // 8 waves (2 per SIMD), single workgroup
#define CPL 4             // columns per lane (8*64*4 = 2048)
#define RPS 16            // rows per wave per step
#define SPW (N / RPS)     // 128 active steps per wave
#define NSTEP (SPW + NW - 1)   // 135 total (systolic skew depth NW-1)

// ---------------------------------------------------------------------------
// Prologue: tab = exp(x) with PADR zero rows appended; fully parallel.
// ---------------------------------------------------------------------------
__global__ void exp_table_kernel(const float* __restrict__ x, float* __restrict__ tab) {
  const int n4  = (N + PADR) * N / 4;
  const int nx4 = N * N / 4;
  const float4* xv = (const float4*)x;
  float4* tv = (float4*)tab;
  for (int i = blockIdx.x * blockDim.x + threadIdx.x; i < n4; i += gridDim.x * blockDim.x) {
    float4 r = make_float4(0.f, 0.f, 0.f, 0.f);
    if (i < nx4) {
      float4 v = xv[i];
      r.x = __expf(v.x); r.y = __expf(v.y); r.z = __expf(v.z); r.w = __expf(v.w);
    }
    tv[i] = r;
  }
}

// ---------------------------------------------------------------------------
// Systolic row-sweep soft SW in exp space. 8 waves (2/SIMD for latency
// overlap), wave w owns columns [256w, 256w+256), lane owns 4 columns.
// At step s wave w does rows 16(s-w)..+15; the same-row left edge
// {S, X'true, M} it consumes was published by wave w-1 LAST step (parity
// double-buffered) -> visible after the single per-step __syncthreads().
// X chain kept in "M units" (X' = X/cGO): X'[0]=M_west, X'[j]=fma(cGE,
// X'[j-1],M[j-1]); T = M + cGO*X' + (cGO*cGE^{j+1})*seed'; 2-term lane
// seed (error e^-8). Y via carried Tg=cGO*T. acc += es*S_diag fuses the
// final logsumexp. ONE shared block exponent per step (16 rows -- the
// R5-proven cadence); red[] parity double-buffered (per-step rescale
// write/read would otherwise race across one barrier). escale corrects
// prev-parity edges published pre-rescale. No atomics, no polling.
// ---------------------------------------------------------------------------
template<bool USE_TAB>
__global__ __launch_bounds__(NW * 64) void sw_sys_kernel(const float* __restrict__ x,
                                                         const float* __restrict__ tab,
                                                         float* __restrict__ out) {
  const int tid  = threadIdx.x;
  const int lane = tid & 63;
  const int w    = tid >> 6;                 // 0..7, wave-uniform
  const int c0   = (w << 8) + lane * CPL;    // lane's first column

  __shared__ float4 edges[2][NW][RPS];       // [parity][wave][row] = {S, X'true, M, 0}
  __shared__ float  red[2][NW];              // [parity][wave] rescale max
  __shared__ float  wsum[NW];                // final sum

  const float cGO = 0.006737946999085467f;   // e^-5
  const float cGE = 0.36787944117144233f;    // e^-1
  const float C4  = 0.01831563888873418f;    // e^-4
  const float K0  = cGO * 0.36787944117144233f;   // cGO*cGE^{j+1}
  const float K1  = cGO * 0.1353352832366127f;
  const float K2  = cGO * 0.049787068367863944f;
  const float K3  = cGO * 0.01831563888873418f;

  float s1_0=0.f, s1_1=0.f, s1_2=0.f, s1_3=0.f;   // prev-row S
  float tg0=0.f, tg1=0.f, tg2=0.f, tg3=0.f;       // cGO * prev-row T
  float yc0=0.f, yc1=0.f, yc2=0.f, yc3=0.f;       // prev-row Y
  float acc=0.f, one=1.f, Lof=0.f, tmx=0.f, escale=1.f, SinC=0.f;

  const bool isL0 = (lane == 0);
  const bool isL1 = (lane == 1);

  const float* src = (USE_TAB ? tab : x) + c0;
  const float* pl  = src + (size_t)4 * N;    // next row to prefetch
  int rown = 4;                              // fallback row counter
  float4 nx0 = *(const float4*)(src);
  float4 nx1 = *(const float4*)(src + N);
  float4 nx2 = *(const float4*)(src + 2 * N);
  float4 nx3 = *(const float4*)(src + 3 * N);

  for (int s = 0; s < NSTEP; ++s) {
    const bool act = (s >= w) && (s < w + SPW);
    const int  pr  = s & 1;
    const int  cr  = pr ^ 1;

    if (act) {
      float prevEdx = 0.f;                   // slot k-1 .x (raw units)

      #pragma unroll
      for (int k = 0; k < RPS; ++k) {
        // ---- row data (rolling 4-deep prefetch; rows are globally sequential) ----
        float4 cur;
        if      ((k & 3) == 0) cur = nx0;
        else if ((k & 3) == 1) cur = nx1;
        else if ((k & 3) == 2) cur = nx2;
        else                   cur = nx3;
        float4 ld;
        if constexpr (USE_TAB) {
          ld = *(const float4*)pl; pl += N;
        } else {
          int rr = (rown < N) ? rown : (N - 1);
          ld = *(const float4*)(src + (size_t)rr * N);
          rown++;
        }
        if      ((k & 3) == 0) nx0 = ld;
        else if ((k & 3) == 1) nx1 = ld;
        else if ((k & 3) == 2) nx2 = ld;
        else                   nx3 = ld;

        float ex0 = cur.x, ex1 = cur.y, ex2 = cur.z, ex3 = cur.w;
        if constexpr (!USE_TAB) {
          ex0 = __expf(ex0); ex1 = __expf(ex1); ex2 = __expf(ex2); ex3 = __expf(ex3);
        }

        // ---- left-wave edge for this row (published last step, other parity) ----
        float4 edc = make_float4(0.f, 0.f, 0.f, 0.f);
        if (w > 0) edc = edges[cr][w - 1][k];
        const float Sr = (k == 0) ? SinC : prevEdx * escale;  // S[r-1] edge
        const float Xi = edc.y * escale;                      // X'true[r] edge
        const float Mi = edc.z * escale;                      // M[r] edge
        prevEdx = edc.x;

        // ---- M / acc (prev-row S shifted right one column) ----
        float sh = __shfl_up(s1_3, 1);
        float s0 = isL0 ? Sr : sh;
        acc = fmaf(ex0, s0,   acc);
        acc = fmaf(ex1, s1_0, acc);
        acc = fmaf(ex2, s1_1, acc);
        acc = fmaf(ex3, s1_2, acc);
        float M0 = ex0 * (s0   + one);
        float M1 = ex1 * (s1_0 + one);
        float M2 = ex2 * (s1_1 + one);
        float M3 = ex3 * (s1_2 + one);

        // ---- X' chain (M units) + 2-term truncated lane seed ----
        float mh = __shfl_up(M3, 1);
        float X0 = isL0 ? Mi : mh;
        float X1 = fmaf(cGE, X0, M0);
        float X2 = fmaf(cGE, X1, M1);
        float X3 = fmaf(cGE, X2, M2);
        float u1 = __shfl_up(X3, 1);
        float u2 = __shfl_up(X3, 2);
        u1 = isL0 ? Xi : u1;
        u2 = isL0 ? 0.f : (isL1 ? Xi : u2);
        float seed = fmaf(C4, u2, u1);

        // ---- T / Y / S ----
        float T0 = fmaf(K0, seed, fmaf(cGO, X0, M0));
        float T1 = fmaf(K1, seed, fmaf(cGO, X1, M1));
        float T2 = fmaf(K2, seed, fmaf(cGO, X2, M2));
        float T3 = fmaf(K3, seed, fmaf(cGO, X3, M3));
        float Y0 = fmaf(cGE, yc0, tg0);
        float Y1 = fmaf(cGE, yc1, tg1);
        float Y2 = fmaf(cGE, yc2, tg2);
        float Y3 = fmaf(cGE, yc3, tg3);
        float S0 = T0 + Y0, S1n = T1 + Y1, S2n = T2 + Y2, S3n = T3 + Y3;

        tmx = fmaxf(tmx, fmaxf(fmaxf(S0, S1n), fmaxf(S2n, S3n)));

        tg0 = cGO * T0; tg1 = cGO * T1; tg2 = cGO * T2; tg3 = cGO * T3;
        yc0 = Y0; yc1 = Y1; yc2 = Y2; yc3 = Y3;
        s1_0 = S0; s1_1 = S1n; s1_2 = S2n; s1_3 = S3n;

        // ---- publish right edge for wave w+1 (consumed next step) ----
        if (w < NW - 1) {
          float xp = fmaf(C4, seed, X3);     // true X' at last col
          if (lane == 63) edges[pr][w][k] = make_float4(S3n, xp, M3, 0.f);
        }
      }
      if (w > 0) SinC = prevEdx * escale;    // slot 15 .x -> next step's Sr[0]
    }

    // ---- per-step block-wide power-of-2 rescale (16 rows) ----
    {
      float m = tmx;
      m = fmaxf(m, __shfl_xor(m, 1));
      m = fmaxf(m, __shfl_xor(m, 2));
      m = fmaxf(m, __shfl_xor(m, 4));
      m = fmaxf(m, __shfl_xor(m, 8));
      m = fmaxf(m, __shfl_xor(m, 16));
      m = fmaxf(m, __shfl_xor(m, 32));
      if (lane == 0) red[pr][w] = m;         // parity buffer: no cross-step race
    }
    __syncthreads();                          // edges + red visible
    {
      float m = fmaxf(fmaxf(fmaxf(red[pr][0], red[pr][1]), fmaxf(red[pr][2], red[pr][3])),
                      fmaxf(fmaxf(red[pr][4], red[pr][5]), fmaxf(red[pr][6], red[pr][7])));
      tmx = 0.f;
      escale = 1.f;
      int e = (m > 0.f) ? ilogbf(m) : 0;
      if (e > 120) e = 120;
      if (e < -120) e = -120;
      if (e != 0) {                          // identical in every wave
        float c = exp2f((float)(-e));
        s1_0 *= c; s1_1 *= c; s1_2 *= c; s1_3 *= c;
        tg0 *= c; tg1 *= c; tg2 *= c; tg3 *= c;
        yc0 *= c; yc1 *= c; yc2 *= c; yc3 *= c;
        acc *= c; one *= c; SinC *= c;
        escale = c;
        Lof += (float)e * 0.6931471805599453f;
      }
    }
  }

  // ---- final reduction: all waves share Lof ----
  float ssum = acc;
  ssum += __shfl_xor(ssum, 1);
  ssum += __shfl_xor(ssum, 2);
  ssum += __shfl_xor(ssum, 4);
  ssum += __shfl_xor(ssum, 8);
  ssum += __shfl_xor(ssum, 16);
  ssum += __shfl_xor(ssum, 32);
  if (lane == 0) wsum[w] = ssum;
  __syncthreads();
  if (tid == 0) {
    double tot = 0.0;
    #pragma unroll
    for (int k = 0; k < NW; ++k) tot += (double)wsum[k];
    out[0] = (float)(log(tot) + (double)Lof);
  }
}

extern "C" void kernel_launch(void* const* d_in, const int* in_sizes, int n_in,
                              void* d_out, int out_size, void* d_ws, size_t ws_size,
                              hipStream_t stream) {
  const float* x = (const float*)d_in[0];
  float* out = (float*)d_out;
  float* tab = (float*)d_ws;
  const size_t need = (size_t)(N + PADR) * N * sizeof(float);
  if (ws_size >= need) {
    exp_table_kernel<<<1024, dim3(256), 0, stream>>>(x, tab);
    sw_sys_kernel<true><<<1, dim3(NW * 64), 0, stream>>>(x, tab, out);
  } else {
    sw_sys_kernel<false><<<1, dim3(NW * 64), 0, stream>>>(x, nullptr, out);
  }
}